// Round 2
// baseline (312.116 us; speedup 1.0000x reference)
//
#include <hip/hip_runtime.h>
#include <math.h>

#define NN 131072
#define KK 27
#define FIN 3
#define FOUT 32
#define EPS 1e-5f

typedef _Float16 f16;
typedef __attribute__((ext_vector_type(8))) _Float16 f16x8;
typedef __attribute__((ext_vector_type(16))) float f32x16;

// ---------------------------------------------------------------------------
// Pack w2 (f32 [27][32][32]) into f16 MFMA B-operand fragments:
// w2p[k][half][lane][j]  (half = which 16 of the 32 input-features)
// B layout for v_mfma_f32_32x32x16: col = lane&31, kdim = (lane>>5)*8 + j
// ---------------------------------------------------------------------------
__global__ __launch_bounds__(256) void pack_w2_kernel(
    const float* __restrict__ w2, f16* __restrict__ w2p)
{
    const int t = blockIdx.x * 256 + threadIdx.x;
    if (t >= KK * 2 * 64 * 8) return;
    const int k    = t >> 10;          // 1024 elems per spatial k
    const int rem  = t & 1023;
    const int half = rem >> 9;
    const int l    = (rem >> 3) & 63;
    const int j    = rem & 7;
    const int krow = half * 16 + ((l >> 5) << 3) + j;  // input-feature row
    const int n    = l & 31;                           // output column
    w2p[t] = (f16)w2[k * (FOUT * FOUT) + krow * FOUT + n];
}

// ---------------------------------------------------------------------------
// Stage x_feats [N,3] f32 -> xpad [N] float4 (x,y,z,0): makes conv1 gathers a
// single aligned dwordx4 per neighbor instead of 3 scalar dwords.
// ---------------------------------------------------------------------------
__global__ __launch_bounds__(256) void pad_x_kernel(
    const float* __restrict__ x, float4* __restrict__ xp)
{
    const int n = blockIdx.x * 256 + threadIdx.x;
    if (n >= NN) return;
    const float* r = x + (size_t)n * 3;
    xp[n] = make_float4(r[0], r[1], r[2], 0.f);
}

// ---------------------------------------------------------------------------
// Phase 1: h = silu(bn1(einsum(x_feats[nbr_idx], w1))) -> [N,32] f16
// K-SPLIT: block = 256 threads, 128 nodes. Waves 0-1 (tid<128) do k=0..13,
// waves 2-3 do k=14..26 (k wave-uniform so w1 stays in SGPRs). Upper half
// stores partial acc to LDS; lower half reduces + BN/SiLU epilogue.
// Doubles TLP (8->16 waves/CU) and halves the per-thread latency chain.
// ---------------------------------------------------------------------------
template<bool PADX>
__global__ __launch_bounds__(256) void conv1_kernel(
    const float*  __restrict__ x_feats,   // [N,3]
    const float4* __restrict__ xpad,      // [N] padded (only if PADX)
    const int*    __restrict__ nbr_idx,   // [N,27]
    const float*  __restrict__ w1,        // [27,3,32]
    const float* __restrict__ g1,  const float* __restrict__ b1,
    const float* __restrict__ m1,  const float* __restrict__ v1,
    f16* __restrict__ h_out)              // [N,32] f16
{
    __shared__ float racc[FOUT][128];

    const int tid   = threadIdx.x;
    const int khalf = tid >> 7;               // wave-uniform k-half
    const int ln    = tid & 127;
    const int n     = blockIdx.x * 128 + ln;
    const int kb    = khalf * 14;             // 0 or 14
    const int kn    = khalf ? 13 : 14;        // wave-uniform

    int idxs[14];
    const int* nb = nbr_idx + (size_t)n * KK + kb;
#pragma unroll
    for (int i = 0; i < 14; ++i)
        if (i < kn) idxs[i] = nb[i];
    __builtin_amdgcn_sched_barrier(0);        // pin idx hoist before gathers

    float acc[FOUT];
#pragma unroll
    for (int o = 0; o < FOUT; ++o) acc[o] = 0.f;

#pragma unroll
    for (int c = 0; c < 2; ++c) {             // 2 chunks of 7 neighbors
        float xs[7][3];
#pragma unroll
        for (int q = 0; q < 7; ++q) {         // 7 gathers in flight
            const int i = c * 7 + q;
            if (i < kn) {
                if (PADX) {
                    const float4 v = xpad[idxs[i]];
                    xs[q][0] = v.x; xs[q][1] = v.y; xs[q][2] = v.z;
                } else {
                    const float* xr = x_feats + (size_t)idxs[i] * FIN;
                    xs[q][0] = xr[0]; xs[q][1] = xr[1]; xs[q][2] = xr[2];
                }
            }
        }
#pragma unroll
        for (int q = 0; q < 7; ++q) {
            const int i = c * 7 + q;
            if (i < kn) {
                const float* w = w1 + (kb + i) * (FIN * FOUT); // uniform->s_load
#pragma unroll
                for (int o = 0; o < FOUT; ++o) {
                    float a = acc[o];
                    a = fmaf(xs[q][0], w[o],            a);
                    a = fmaf(xs[q][1], w[FOUT + o],     a);
                    a = fmaf(xs[q][2], w[2 * FOUT + o], a);
                    acc[o] = a;
                }
            }
        }
    }

    if (khalf) {                              // upper half: park partials
#pragma unroll
        for (int o = 0; o < FOUT; ++o) racc[o][ln] = acc[o];
    }
    __syncthreads();
    if (khalf) return;

#pragma unroll
    for (int o = 0; o < FOUT; ++o) acc[o] += racc[o][ln];

    f16* hr = h_out + (size_t)n * FOUT;
#pragma unroll
    for (int g = 0; g < 4; ++g) {
        f16x8 hv;
#pragma unroll
        for (int j = 0; j < 8; ++j) {
            const int o = g * 8 + j;
            const float sc = g1[o] * rsqrtf(v1[o] + EPS);
            float v = (acc[o] - m1[o]) * sc + b1[o];
            v = v / (1.f + __expf(-v));              // silu
            hv[j] = (f16)v;
        }
        *(f16x8*)(hr + g * 8) = hv;                  // 16B stores
    }
}

// ---------------------------------------------------------------------------
// Phase 2 (MFMA): x_out = einsum(h[nbr_idx], w2) via v_mfma_f32_32x32x16_f16.
// K-SPLIT: block = 4 waves = 2 node-groups of 32. Within each pair, the even
// wave does k=0..13, the odd wave k=14..26. Even wave parks its 32x32 partial
// C tile in LDS; odd wave reduces and runs the fused point-branch epilogue.
// Doubles grid TLP and halves each wave's gather-latency chain. idx hoist is
// pinned with sched_barrier (last round's VGPR=48 proved the compiler sank
// the idx loads into the loop -> serial idx->gather chains).
// ---------------------------------------------------------------------------
__global__ __launch_bounds__(256) void conv2_mfma_kernel(
    const f16*   __restrict__ h,         // [N,32] f16
    const int*   __restrict__ nbr_idx,   // [N,27]
    const f16*   __restrict__ w2p,       // packed [27][2][64][8] f16
    const float* __restrict__ z_feats,   // [N,3]
    const float* __restrict__ mlp_w,     // [3,32]
    const float* __restrict__ mlp_b,
    const float* __restrict__ mg, const float* __restrict__ mbe,
    const float* __restrict__ mm, const float* __restrict__ mv,
    float* __restrict__ out)             // [2,N,32]
{
    __shared__ float red[2][16][64];     // partial C tiles, 8 KiB

    const int lane = threadIdx.x & 63;
    const int wave = threadIdx.x >> 6;
    const int pair = wave >> 1;                      // node-group in block
    const int kodd = wave & 1;                       // wave-uniform k-half
    const int base = (blockIdx.x * 2 + pair) * 32;   // node base
    const int row  = lane & 31;                      // A row
    const int hi   = lane >> 5;                      // which k-half of 8

    const int kb = kodd ? 14 : 0;
    const int kn = kodd ? 13 : 14;

    // hoist this wave's neighbor indices (disjoint halves between the pair)
    int idxs[14];
    const int* nb = nbr_idx + (size_t)(base + row) * KK + kb;
#pragma unroll
    for (int i = 0; i < 14; ++i)
        if (i < kn) idxs[i] = nb[i];
    __builtin_amdgcn_sched_barrier(0);   // pin hoist: 14 idx loads in flight

    f32x16 acc0 = {};                                // even-k accumulator
    f32x16 acc1 = {};                                // odd-k accumulator

    const f16x8* bpk = (const f16x8*)w2p + (size_t)kb * 128;

    // prologue: first k of this wave's range
    f16x8 a1, a2, b1, b2;
    {
        const f16* hr = h + (size_t)idxs[0] * FOUT + hi * 8;
        a1 = *(const f16x8*)hr;
        a2 = *(const f16x8*)(hr + 16);
        b1 = bpk[lane];
        b2 = bpk[64 + lane];
    }

#pragma unroll
    for (int i = 0; i < 14; ++i) {
        if (i >= kn) break;                          // wave-uniform
        f16x8 na1, na2;
        const bool more = (i + 1 < kn);
        if (more) {                                  // prefetch next gather
            const f16* hr = h + (size_t)idxs[i + 1] * FOUT + hi * 8;
            na1 = *(const f16x8*)hr;
            na2 = *(const f16x8*)(hr + 16);
        }
        __builtin_amdgcn_s_setprio(1);
        acc0 = __builtin_amdgcn_mfma_f32_32x32x16_f16(a1, b1, acc0, 0, 0, 0);
        acc1 = __builtin_amdgcn_mfma_f32_32x32x16_f16(a2, b2, acc1, 0, 0, 0);
        __builtin_amdgcn_s_setprio(0);
        if (more) {
            a1 = na1; a2 = na2;                      // rotate pipeline regs
            b1 = bpk[(i + 1) * 128 + lane];          // B is L1-hot, shallow
            b2 = bpk[(i + 1) * 128 + 64 + lane];
        }
    }

    if (!kodd) {                                     // even wave: park tile
#pragma unroll
        for (int r = 0; r < 16; ++r) red[pair][r][lane] = acc0[r] + acc1[r];
    }
    __syncthreads();
    if (!kodd) return;

    // ---- odd wave: reduce + point branch for column n0, fused add + store --
    const int n0 = lane & 31;
    const float wc0 = mlp_w[n0];
    const float wc1 = mlp_w[FOUT + n0];
    const float wc2 = mlp_w[2 * FOUT + n0];
    const float sc  = mg[n0] * rsqrtf(mv[n0] + EPS);
    const float bi  = mlp_b[n0];
    const float mmv = mm[n0];
    const float mbv = mbe[n0];

#pragma unroll
    for (int r = 0; r < 16; ++r) {
        const int m    = (r & 3) + ((r >> 2) << 3) + (hi << 2); // C/D row map
        const int node = base + m;
        const float* zr = z_feats + (size_t)node * FIN;
        float z = bi;
        z = fmaf(zr[0], wc0, z);
        z = fmaf(zr[1], wc1, z);
        z = fmaf(zr[2], wc2, z);
        z = (z - mmv) * sc + mbv;
        z = fmaxf(z, 0.f);
        const float v = acc0[r] + acc1[r] + red[pair][r][lane] + z;
        out[(size_t)node * FOUT + n0] = v;
        out[(size_t)NN * FOUT + (size_t)node * FOUT + n0] = v;
    }
}

extern "C" void kernel_launch(void* const* d_in, const int* in_sizes, int n_in,
                              void* d_out, int out_size, void* d_ws, size_t ws_size,
                              hipStream_t stream) {
    const float* x_feats = (const float*)d_in[0];
    const float* z_feats = (const float*)d_in[1];
    const int*   nbr_idx = (const int*)d_in[2];
    const float* w1      = (const float*)d_in[3];
    const float* bn1_g   = (const float*)d_in[4];
    const float* bn1_b   = (const float*)d_in[5];
    const float* bn1_m   = (const float*)d_in[6];
    const float* bn1_v   = (const float*)d_in[7];
    const float* w2      = (const float*)d_in[8];
    const float* mlp_w   = (const float*)d_in[9];
    const float* mlp_b   = (const float*)d_in[10];
    const float* mlp_g   = (const float*)d_in[11];
    const float* mlp_be  = (const float*)d_in[12];
    const float* mlp_m   = (const float*)d_in[13];
    const float* mlp_v   = (const float*)d_in[14];

    const size_t OFF_W2P  = (size_t)8 * 1024 * 1024;   // h:   [0, 8 MiB)
    const size_t OFF_XPAD = (size_t)9 * 1024 * 1024;   // w2p: [8M, 8M+54K)
    const size_t XPAD_SZ  = (size_t)NN * 16;           // xpad: [9M, 11M)

    f16*    h    = (f16*)d_ws;
    f16*    w2p  = (f16*)((char*)d_ws + OFF_W2P);
    float4* xpad = (float4*)((char*)d_ws + OFF_XPAD);
    const bool padx = ws_size >= OFF_XPAD + XPAD_SZ;
    float* out = (float*)d_out;

    pack_w2_kernel<<<(KK * 1024 + 255) / 256, 256, 0, stream>>>(w2, w2p);
    if (padx) {
        pad_x_kernel<<<NN / 256, 256, 0, stream>>>(x_feats, xpad);
        conv1_kernel<true><<<NN / 128, 256, 0, stream>>>(
            x_feats, xpad, nbr_idx, w1, bn1_g, bn1_b, bn1_m, bn1_v, h);
    } else {
        conv1_kernel<false><<<NN / 128, 256, 0, stream>>>(
            x_feats, xpad, nbr_idx, w1, bn1_g, bn1_b, bn1_m, bn1_v, h);
    }
    conv2_mfma_kernel<<<NN / 64, 256, 0, stream>>>(h, nbr_idx, w2p, z_feats,
                                                   mlp_w, mlp_b, mlp_g, mlp_be,
                                                   mlp_m, mlp_v, out);
}

// Round 3
// 201.869 us; speedup vs baseline: 1.5461x; 1.5461x over previous
//
#include <hip/hip_runtime.h>
#include <math.h>

#define NN 131072
#define KK 27
#define KP 28          // K padded to 28; slot 27 is all-zero weights
#define FIN 3
#define FOUT 32
#define EPS 1e-5f

typedef _Float16 f16;
typedef __attribute__((ext_vector_type(8))) _Float16 f16x8;
typedef __attribute__((ext_vector_type(16))) float f32x16;

// ---------------------------------------------------------------------------
// Pack w2 into f16 MFMA B-fragments w2p[k][half][lane][j] with a zero k=27
// slot, and w1 -> w1p [28][3][32] with a zero k=27 row (lets both conv
// kernels run compile-time-constant K/2 loops with no predication).
// B layout for v_mfma_f32_32x32x16: col = lane&31, kdim = (lane>>5)*8 + j
// ---------------------------------------------------------------------------
__global__ __launch_bounds__(256) void pack_kernel(
    const float* __restrict__ w2, const float* __restrict__ w1,
    f16* __restrict__ w2p, float* __restrict__ w1p)
{
    const int t = blockIdx.x * 256 + threadIdx.x;
    if (t < KP * 1024) {
        const int k    = t >> 10;          // 1024 elems per spatial k
        const int rem  = t & 1023;
        const int half = rem >> 9;
        const int l    = (rem >> 3) & 63;
        const int j    = rem & 7;
        const int krow = half * 16 + ((l >> 5) << 3) + j;  // input-feature row
        const int n    = l & 31;                           // output column
        w2p[t] = (k < KK) ? (f16)w2[k * (FOUT * FOUT) + krow * FOUT + n]
                          : (f16)0.f;
    } else {
        const int u = t - KP * 1024;
        if (u < KP * FIN * FOUT) {
            const int k = u / (FIN * FOUT);
            w1p[u] = (k < KK) ? w1[u] : 0.f;
        }
    }
}

// ---------------------------------------------------------------------------
// Stage x_feats [N,3] f32 -> xpad [N] float4 (x,y,z,0): one aligned dwordx4
// gather per neighbor instead of 3 scalar dwords (3x fewer L1 transactions).
// ---------------------------------------------------------------------------
__global__ __launch_bounds__(256) void pad_x_kernel(
    const float* __restrict__ x, float4* __restrict__ xp)
{
    const int n = blockIdx.x * 256 + threadIdx.x;
    if (n >= NN) return;
    const float* r = x + (size_t)n * 3;
    xp[n] = make_float4(r[0], r[1], r[2], 0.f);
}

// ---------------------------------------------------------------------------
// Phase 1: h = silu(bn1(einsum(x[nbr_idx], w1))) -> [N,32] f16
// K-SPLIT, compile-time trip count: block = 256 thr / 128 nodes. tid<128 does
// k=0..13, tid>=128 does k=14..27 (27 = zero pad -> contributes 0). Upper
// half parks partials in LDS; lower half reduces + BN/SiLU epilogue.
// NO sched_barrier (round-2 spill disaster); idx hoist pinned per-value.
// ---------------------------------------------------------------------------
__global__ __launch_bounds__(256) void conv1_kernel(
    const float4* __restrict__ xpad,      // [N] padded x
    const int*    __restrict__ nbr_idx,   // [N,27]
    const float*  __restrict__ w1p,       // [28,3,32] (k=27 zeros)
    const float* __restrict__ g1,  const float* __restrict__ b1,
    const float* __restrict__ m1,  const float* __restrict__ v1,
    f16* __restrict__ h_out)              // [N,32] f16
{
    __shared__ float racc[FOUT][128];     // 16 KiB

    const int tid   = threadIdx.x;
    const int khalf = tid >> 7;               // wave-uniform k-half
    const int ln    = tid & 127;
    const int n     = blockIdx.x * 128 + ln;
    const int kb    = khalf * 14;             // 0 or 14

    // hoist 14 neighbor indices; clamp the pad slot in-bounds (k==27)
    int idxs[14];
    const int* nb = nbr_idx + (size_t)n * KK + kb;
#pragma unroll
    for (int i = 0; i < 14; ++i) {
        const int off = (kb + i < KK) ? i : 0;     // wave-uniform select
        idxs[i] = nb[off];
    }
#pragma unroll
    for (int i = 0; i < 14; ++i) asm volatile("" : "+v"(idxs[i]));

    float acc[FOUT];
#pragma unroll
    for (int o = 0; o < FOUT; ++o) acc[o] = 0.f;

#pragma unroll
    for (int c = 0; c < 2; ++c) {             // 2 chunks of 7 neighbors
        float4 xs[7];
#pragma unroll
        for (int q = 0; q < 7; ++q)           // 7 float4 gathers in flight
            xs[q] = xpad[idxs[c * 7 + q]];
#pragma unroll
        for (int q = 0; q < 7; ++q) {
            const float* w = w1p + (kb + c * 7 + q) * (FIN * FOUT); // s_load
#pragma unroll
            for (int o = 0; o < FOUT; ++o) {
                float a = acc[o];
                a = fmaf(xs[q].x, w[o],            a);
                a = fmaf(xs[q].y, w[FOUT + o],     a);
                a = fmaf(xs[q].z, w[2 * FOUT + o], a);
                acc[o] = a;
            }
        }
    }

    if (khalf) {                              // upper half: park partials
#pragma unroll
        for (int o = 0; o < FOUT; ++o) racc[o][ln] = acc[o];
    }
    __syncthreads();
    if (khalf) return;

#pragma unroll
    for (int o = 0; o < FOUT; ++o) acc[o] += racc[o][ln];

    f16* hr = h_out + (size_t)n * FOUT;
#pragma unroll
    for (int g = 0; g < 4; ++g) {
        f16x8 hv;
#pragma unroll
        for (int j = 0; j < 8; ++j) {
            const int o = g * 8 + j;
            const float sc = g1[o] * rsqrtf(v1[o] + EPS);
            float v = (acc[o] - m1[o]) * sc + b1[o];
            v = v / (1.f + __expf(-v));              // silu
            hv[j] = (f16)v;
        }
        *(f16x8*)(hr + g * 8) = hv;                  // 16B stores
    }
}

// ---------------------------------------------------------------------------
// Phase 2 (MFMA): x_out = einsum(h[nbr_idx], w2) via v_mfma_f32_32x32x16_f16.
// One wave = 32 nodes, straight k=0..26, dual accumulators, and an explicit
// DEPTH-6 rolling gather window (fully unrolled -> static reg indices) so
// ~12 scattered 16B loads stay in flight per wave against L3/HBM latency.
// Idx hoist pinned per-value (round-1 VGPR=48 proved the hoist was sunk).
// Point-branch MLP+BN+ReLU fused in epilogue; all 64 lanes participate.
// ---------------------------------------------------------------------------
__global__ __launch_bounds__(256) void conv2_mfma_kernel(
    const f16*   __restrict__ h,         // [N,32] f16
    const int*   __restrict__ nbr_idx,   // [N,27]
    const f16*   __restrict__ w2p,       // packed [28][2][64][8] f16
    const float* __restrict__ z_feats,   // [N,3]
    const float* __restrict__ mlp_w,     // [3,32]
    const float* __restrict__ mlp_b,
    const float* __restrict__ mg, const float* __restrict__ mbe,
    const float* __restrict__ mm, const float* __restrict__ mv,
    float* __restrict__ out)             // [2,N,32]
{
    const int lane = threadIdx.x & 63;
    const int wave = threadIdx.x >> 6;
    const int base = (blockIdx.x * 4 + wave) * 32;   // this wave's node base
    const int row  = lane & 31;                      // A row
    const int hi   = lane >> 5;                      // which k-half of 8

    // hoist all 27 neighbor indices, pinned so they issue before the loop
    int idxs[KK];
    const int* nb = nbr_idx + (size_t)(base + row) * KK;
#pragma unroll
    for (int k = 0; k < KK; ++k) idxs[k] = nb[k];
#pragma unroll
    for (int k = 0; k < KK; ++k) asm volatile("" : "+v"(idxs[k]));

    f32x16 acc0 = {};                                // even-position acc
    f32x16 acc1 = {};                                // odd-position acc

    const f16x8* bp = (const f16x8*)w2p;             // [k*128 + half*64 + lane]

    constexpr int D = 6;                             // gather window depth
    f16x8 A1[KK], A2[KK];                            // short live ranges

#pragma unroll
    for (int k = 0; k < D; ++k) {                    // prologue: fill window
        const f16* hr = h + (size_t)idxs[k] * FOUT + hi * 8;
        A1[k] = *(const f16x8*)hr;
        A2[k] = *(const f16x8*)(hr + 16);
    }

#pragma unroll
    for (int k = 0; k < KK; ++k) {
        if (k + D < KK) {                            // compile-time predicate
            const f16* hr = h + (size_t)idxs[k + D] * FOUT + hi * 8;
            A1[k + D] = *(const f16x8*)hr;
            A2[k + D] = *(const f16x8*)(hr + 16);
        }
        const f16x8 b1 = bp[k * 128 + lane];         // w2p is L1/L2-hot
        const f16x8 b2 = bp[k * 128 + 64 + lane];
        __builtin_amdgcn_s_setprio(1);
        acc0 = __builtin_amdgcn_mfma_f32_32x32x16_f16(A1[k], b1, acc0, 0, 0, 0);
        acc1 = __builtin_amdgcn_mfma_f32_32x32x16_f16(A2[k], b2, acc1, 0, 0, 0);
        __builtin_amdgcn_s_setprio(0);
    }

    // ---- epilogue: point branch for output column n0, fused add + store ----
    const int n0 = lane & 31;
    const float wc0 = mlp_w[n0];
    const float wc1 = mlp_w[FOUT + n0];
    const float wc2 = mlp_w[2 * FOUT + n0];
    const float sc  = mg[n0] * rsqrtf(mv[n0] + EPS);
    const float bi  = mlp_b[n0];
    const float mmv = mm[n0];
    const float mbv = mbe[n0];

#pragma unroll
    for (int r = 0; r < 16; ++r) {
        const int m    = (r & 3) + ((r >> 2) << 3) + (hi << 2); // C/D row map
        const int node = base + m;
        const float* zr = z_feats + (size_t)node * FIN;
        float z = bi;
        z = fmaf(zr[0], wc0, z);
        z = fmaf(zr[1], wc1, z);
        z = fmaf(zr[2], wc2, z);
        z = (z - mmv) * sc + mbv;
        z = fmaxf(z, 0.f);
        const float v = acc0[r] + acc1[r] + z;
        out[(size_t)node * FOUT + n0] = v;
        out[(size_t)NN * FOUT + (size_t)node * FOUT + n0] = v;
    }
}

extern "C" void kernel_launch(void* const* d_in, const int* in_sizes, int n_in,
                              void* d_out, int out_size, void* d_ws, size_t ws_size,
                              hipStream_t stream) {
    const float* x_feats = (const float*)d_in[0];
    const float* z_feats = (const float*)d_in[1];
    const int*   nbr_idx = (const int*)d_in[2];
    const float* w1      = (const float*)d_in[3];
    const float* bn1_g   = (const float*)d_in[4];
    const float* bn1_b   = (const float*)d_in[5];
    const float* bn1_m   = (const float*)d_in[6];
    const float* bn1_v   = (const float*)d_in[7];
    const float* w2      = (const float*)d_in[8];
    const float* mlp_w   = (const float*)d_in[9];
    const float* mlp_b   = (const float*)d_in[10];
    const float* mlp_g   = (const float*)d_in[11];
    const float* mlp_be  = (const float*)d_in[12];
    const float* mlp_m   = (const float*)d_in[13];
    const float* mlp_v   = (const float*)d_in[14];

    // workspace layout (round-2 run proved ws_size >= 11 MiB):
    //   h    [0, 8M)      w2p [8M, 8M+56K)   w1p [8M+64K, +10.5K)
    //   xpad [9M, 11M)
    const size_t OFF_W2P  = (size_t)8 * 1024 * 1024;
    const size_t OFF_W1P  = OFF_W2P + 64 * 1024;
    const size_t OFF_XPAD = (size_t)9 * 1024 * 1024;

    f16*    h    = (f16*)d_ws;
    f16*    w2p  = (f16*)((char*)d_ws + OFF_W2P);
    float*  w1p  = (float*)((char*)d_ws + OFF_W1P);
    float4* xpad = (float4*)((char*)d_ws + OFF_XPAD);
    float* out = (float*)d_out;

    const int pack_elems = KP * 1024 + KP * FIN * FOUT;
    pack_kernel<<<(pack_elems + 255) / 256, 256, 0, stream>>>(w2, w1, w2p, w1p);
    pad_x_kernel<<<NN / 256, 256, 0, stream>>>(x_feats, xpad);
    conv1_kernel<<<NN / 128, 256, 0, stream>>>(xpad, nbr_idx, w1p,
                                               bn1_g, bn1_b, bn1_m, bn1_v, h);
    conv2_mfma_kernel<<<NN / 128, 256, 0, stream>>>(h, nbr_idx, w2p, z_feats,
                                                    mlp_w, mlp_b, mlp_g, mlp_be,
                                                    mlp_m, mlp_v, out);
}